// Round 8
// baseline (854.811 us; speedup 1.0000x reference)
//
#include <hip/hip_runtime.h>

#define T_LEN 512
#define OSTRIDE ((size_t)2048 * 512 * 32)  // elements per output copy

typedef float v2f __attribute__((ext_vector_type(2)));
#define PKFMA(a, b, c) __builtin_elementwise_fma((a), (b), (c))

__device__ __forceinline__ float rlf(float v, int l) {
  return __int_as_float(__builtin_amdgcn_readlane(__float_as_int(v), l));
}
// quad_perm broadcast of quad-lane sel (0..3): ctrl = sel * 0x55
#define QB(v, pat) __int_as_float(__builtin_amdgcn_mov_dpp(__float_as_int(v), (pat), 0xF, 0xF, false))

// ===========================================================================
// Setup kernel (unchanged from r6).
// ===========================================================================
__global__ __launch_bounds__(64) void setup_kernel(
    const float* __restrict__ Wih, const float* __restrict__ bih,
    const float* __restrict__ bhh, const float* __restrict__ w3,
    const float* __restrict__ b3, float* __restrict__ Wz,
    float* __restrict__ Bz) {
  const int g = threadIdx.x;  // 0..63
  const float sK = ((g >> 4) == 2) ? 2.0f : -1.0f;
  float acc[16];
#pragma unroll
  for (int k = 0; k < 16; ++k) acc[k] = 0.f;
  float bz = bih[g] + bhh[g];
#pragma unroll
  for (int j = 0; j < 16; ++j) {
    const float wij = Wih[g * 16 + j];
#pragma unroll
    for (int k = 0; k < 16; ++k)
      acc[k] = __builtin_fmaf(wij, w3[j * 16 + k], acc[k]);
    bz = __builtin_fmaf(wij, b3[j], bz);
  }
#pragma unroll
  for (int k = 0; k < 16; ++k) Wz[g * 16 + k] = sK * acc[k];
  Bz[g] = sK * bz;
}

// ===========================================================================
// Pre-net kernel (unchanged from r6): layers 1-2 -> y2 (64 MB), xstart.
// ===========================================================================
__global__ __launch_bounds__(256) void prenet_y2_kernel(
    const float* __restrict__ seq,
    const float* __restrict__ w1, const float* __restrict__ b1,
    const float* __restrict__ w2, const float* __restrict__ b2,
    const float* __restrict__ w3, const float* __restrict__ b3,
    float* __restrict__ y2g, float* __restrict__ xstart) {
  const int tid = threadIdx.x;
  const size_t r = (size_t)blockIdx.x * 256 + tid;

  const float* sp = seq + r * 32;
  float in[32];
#pragma unroll
  for (int q = 0; q < 8; ++q) {
    float4 v = ((const float4*)sp)[q];
    in[q * 4 + 0] = v.x;
    in[q * 4 + 1] = v.y;
    in[q * 4 + 2] = v.z;
    in[q * 4 + 3] = v.w;
  }

  float y1[16];
#pragma unroll
  for (int j = 0; j < 16; ++j) {
    float a0 = b1[j], a1 = 0.f, a2 = 0.f, a3 = 0.f;
#pragma unroll
    for (int k = 0; k < 32; k += 4) {
      a0 = __builtin_fmaf(w1[j * 32 + k + 0], in[k + 0], a0);
      a1 = __builtin_fmaf(w1[j * 32 + k + 1], in[k + 1], a1);
      a2 = __builtin_fmaf(w1[j * 32 + k + 2], in[k + 2], a2);
      a3 = __builtin_fmaf(w1[j * 32 + k + 3], in[k + 3], a3);
    }
    float s = (a0 + a1) + (a2 + a3);
    y1[j] = s >= 0.f ? s : 0.01f * s;
  }

  float y2[16];
#pragma unroll
  for (int j = 0; j < 16; ++j) {
    float a0 = b2[j], a1 = 0.f, a2 = 0.f, a3 = 0.f;
#pragma unroll
    for (int k = 0; k < 16; k += 4) {
      a0 = __builtin_fmaf(w2[j * 16 + k + 0], y1[k + 0], a0);
      a1 = __builtin_fmaf(w2[j * 16 + k + 1], y1[k + 1], a1);
      a2 = __builtin_fmaf(w2[j * 16 + k + 2], y1[k + 2], a2);
      a3 = __builtin_fmaf(w2[j * 16 + k + 3], y1[k + 3], a3);
    }
    float s = (a0 + a1) + (a2 + a3);
    y2[j] = s >= 0.f ? s : 0.01f * s;
  }

  float* op = y2g + r * 16;
#pragma unroll
  for (int q = 0; q < 4; ++q)
    ((float4*)op)[q] = make_float4(y2[q * 4 + 0], y2[q * 4 + 1],
                                   y2[q * 4 + 2], y2[q * 4 + 3]);

  if ((r & (T_LEN - 1)) == (T_LEN - 1)) {
    float y3[16];
#pragma unroll
    for (int j = 0; j < 16; ++j) {
      float a0 = b3[j], a1 = 0.f, a2 = 0.f, a3 = 0.f;
#pragma unroll
      for (int k = 0; k < 16; k += 4) {
        a0 = __builtin_fmaf(w3[j * 16 + k + 0], y2[k + 0], a0);
        a1 = __builtin_fmaf(w3[j * 16 + k + 1], y2[k + 1], a1);
        a2 = __builtin_fmaf(w3[j * 16 + k + 2], y2[k + 2], a2);
        a3 = __builtin_fmaf(w3[j * 16 + k + 3], y2[k + 3], a3);
      }
      y3[j] = (a0 + a1) + (a2 + a3);
    }
    float* xs = xstart + (r >> 9) * 16;
#pragma unroll
    for (int q = 0; q < 4; ++q)
      ((float4*)xs)[q] = make_float4(y3[q * 4 + 0], y3[q * 4 + 1],
                                     y3[q * 4 + 2], y3[q * 4 + 3]);
  }
}

// ===========================================================================
// Parameterized cell macros (same FP order as r6; state passed explicitly so
// one wave can carry TWO independent chains).
// ===========================================================================
#define ACT_P(G, H, C, HK)                                                  \
  do {                                                                      \
    float ee_ = __expf(G);                                                  \
    float rr_ = __builtin_amdgcn_rcpf(1.0f + ee_);                          \
    float act_ = __builtin_fmaf(sa, rr_, sb);                               \
    float ii_ = QB(act_, 0x00);                                             \
    float ff_ = QB(act_, 0x55);                                             \
    float gg_ = QB(act_, 0xAA);                                             \
    float oo_ = QB(act_, 0xFF);                                             \
    C = __builtin_fmaf(ff_, C, ii_ * gg_);                                  \
    float th_ = __builtin_fmaf(                                             \
        -2.0f, __builtin_amdgcn_rcpf(1.0f + __expf(C + C)), 1.0f);          \
    H = oo_ * th_;                                                          \
    _Pragma("unroll") for (int m = 0; m < 8; ++m) {                         \
      HK[m].x = rlf(H, 8 * m);                                              \
      HK[m].y = rlf(H, 8 * m + 4);                                          \
    }                                                                       \
  } while (0)

#define CELLZ_P(ZV, H, C, HK)                                               \
  do {                                                                      \
    v2f A_, B_;                                                             \
    A_.x = (ZV); A_.y = 0.f; B_.x = 0.f; B_.y = 0.f;                        \
    _Pragma("unroll") for (int m = 0; m < 8; m += 2) {                      \
      A_ = PKFMA(whh2[m], HK[m], A_);                                       \
      B_ = PKFMA(whh2[m + 1], HK[m + 1], B_);                               \
    }                                                                       \
    float g_ = (A_.x + A_.y) + (B_.x + B_.y);                               \
    ACT_P(g_, H, C, HK);                                                    \
  } while (0)

#define CELL_P(WX2, XA2, BB, H, C, HK)                                      \
  do {                                                                      \
    v2f A_, B_;                                                             \
    A_.x = (BB); A_.y = 0.f; B_.x = 0.f; B_.y = 0.f;                        \
    _Pragma("unroll") for (int m = 0; m < 8; m += 2) {                      \
      A_ = PKFMA(WX2[m], XA2[m], A_);                                       \
      B_ = PKFMA(WX2[m + 1], XA2[m + 1], B_);                               \
    }                                                                       \
    _Pragma("unroll") for (int m = 0; m < 8; m += 2) {                      \
      A_ = PKFMA(whh2[m], HK[m], A_);                                       \
      B_ = PKFMA(whh2[m + 1], HK[m + 1], B_);                               \
    }                                                                       \
    float g_ = (A_.x + A_.y) + (B_.x + B_.y);                               \
    ACT_P(g_, H, C, HK);                                                    \
  } while (0)

// z-gate GEMV (exact original phase-B order).
#define ZGEMV_P(YQ, OUTV)                                                   \
  do {                                                                      \
    v2f A_, B_;                                                             \
    A_.x = bz; A_.y = 0.f; B_.x = 0.f; B_.y = 0.f;                          \
    _Pragma("unroll") for (int q = 0; q < 4; ++q) {                         \
      float4 v_ = (YQ)[q];                                                  \
      v2f ylo_, yhi_;                                                       \
      ylo_.x = v_.x; ylo_.y = v_.y; yhi_.x = v_.z; yhi_.y = v_.w;           \
      A_ = PKFMA(wz2[2 * q + 0], ylo_, A_);                                 \
      B_ = PKFMA(wz2[2 * q + 1], yhi_, B_);                                 \
    }                                                                       \
    OUTV = (A_.x + A_.y) + (B_.x + B_.y);                                   \
  } while (0)

#define LDY(RING, YB, ROW)                                                  \
  do {                                                                      \
    _Pragma("unroll") for (int q = 0; q < 4; ++q)                           \
      RING[q] = (YB)[(size_t)(ROW) * 4 + q];                                \
  } while (0)

// ===========================================================================
// Recurrence kernel, TWO batch elements per wave (1024 waves = 1 wave/SIMD).
// The 23% VALU-idle at 2 waves/SIMD is co-stall: both waves run identical
// code and hit the same exp/readlane latency simultaneously. Two independent
// chains interleaved IN-WAVE give the scheduler guaranteed fill ops.
// Weights shared across chains; each chain runs the exact r6 op sequence ->
// bit-identical output. launch_bounds(256,1): 1 wave/EU -> VGPR cap ~512.
// ===========================================================================
__global__ __launch_bounds__(256, 1) void lstm_rec_z2_kernel(
    const float* __restrict__ Whh, const float* __restrict__ Wih,
    const float* __restrict__ bih, const float* __restrict__ bhh,
    const float* __restrict__ hw1, const float* __restrict__ hb1,
    const float* __restrict__ hw2, const float* __restrict__ hb2,
    const float* __restrict__ pw, const float* __restrict__ pb,
    const float* __restrict__ Wz, const float* __restrict__ Bz,
    const float* __restrict__ y2g, const float* __restrict__ xstart,
    float* __restrict__ out) {
  const int lane = threadIdx.x & 63;
  const int wid = threadIdx.x >> 6;
  const int bu0 =
      __builtin_amdgcn_readfirstlane(blockIdx.x * 8 + wid * 2);  // chain A
  const int bu1 = bu0 + 1;                                       // chain B
  const int hr = lane >> 2;             // h index 0..15 (quad id)
  const int gi = (lane & 3) * 16 + hr;  // gate row 0..63
  const bool isT = (lane & 3) == 2;     // quad-lane 2 = g gate (tanh)

  const float sK = isT ? 2.0f : -1.0f;
  const float sa = isT ? -2.0f : 1.0f;
  const float sb = isT ? 1.0f : 0.0f;

  v2f whh2[8];
#pragma unroll
  for (int m = 0; m < 8; ++m) {
    whh2[m].x = Whh[gi * 16 + 2 * m + 0] * sK;
    whh2[m].y = Whh[gi * 16 + 2 * m + 1] * sK;
  }

  v2f wz2[8];
  {
    const float4* wzv = (const float4*)(Wz + gi * 16);
#pragma unroll
    for (int q = 0; q < 4; ++q) {
      float4 v = wzv[q];
      wz2[2 * q + 0].x = v.x;
      wz2[2 * q + 0].y = v.y;
      wz2[2 * q + 1].x = v.z;
      wz2[2 * q + 1].y = v.w;
    }
  }
  const float bz = Bz[gi];

  float hA = 0.f, cA = 0.f, hB = 0.f, cB = 0.f;
  v2f hkA[8], hkB[8];
#pragma unroll
  for (int m = 0; m < 8; ++m) {
    hkA[m].x = 0.f; hkA[m].y = 0.f;
    hkB[m].x = 0.f; hkB[m].y = 0.f;
  }

  // -------- encoder: 512 steps, rings 4 ahead per chain, zv pipelined 1 ----
  const float4* ybA = (const float4*)(y2g + (size_t)bu0 * (T_LEN * 16));
  const float4* ybB = (const float4*)(y2g + (size_t)bu1 * (T_LEN * 16));
  float4 yqA[4][4], yqB[4][4];
#pragma unroll
  for (int u = 0; u < 4; ++u) {
    LDY(yqA[u], ybA, u);
    LDY(yqB[u], ybB, u);
  }
  __builtin_amdgcn_sched_barrier(0);  // prologue loads issue before the loop

  float zcA, zcB;
  ZGEMV_P(yqA[0], zcA);
  ZGEMV_P(yqB[0], zcB);

  for (int t0 = 0; t0 < T_LEN; t0 += 4) {
#pragma unroll
    for (int u = 0; u < 4; ++u) {
      // znext of both chains is h-independent: fills the act-chain stalls.
      float znA, znB;
      ZGEMV_P(yqA[(u + 1) & 3], znA);
      ZGEMV_P(yqB[(u + 1) & 3], znB);
      CELLZ_P(zcA, hA, cA, hkA);
      CELLZ_P(zcB, hB, cB, hkB);
      int tn = t0 + u + 4;
      tn = tn < T_LEN ? tn : (T_LEN - 1);  // tail reload, discarded
      LDY(yqA[u], ybA, tn);
      LDY(yqB[u], ybB, tn);
      // Pin issue order (r5-proven): refills may NOT sink past here.
      __builtin_amdgcn_sched_barrier(0);
      zcA = znA;
      zcB = znB;
    }
  }

  // ---------------- decoder setup (weights shared) ----------------
  v2f wih2[8];
#pragma unroll
  for (int m = 0; m < 8; ++m) {
    wih2[m].x = Wih[gi * 16 + 2 * m + 0] * sK;
    wih2[m].y = Wih[gi * 16 + 2 * m + 1] * sK;
  }
  const float bias = (bih[gi] + bhh[gi]) * sK;

  const int mrow = (lane < 32) ? lane : (lane & 15);
  const float* msrc = (lane < 32) ? (pw + mrow * 16) : (hw1 + mrow * 16);
  const float mbias = (lane < 32) ? pb[mrow] : hb1[mrow];
  const float sl = (lane < 32) ? 1.0f : 0.01f;
  v2f mr2[8];
#pragma unroll
  for (int m = 0; m < 8; ++m) {
    mr2[m].x = msrc[2 * m + 0];
    mr2[m].y = msrc[2 * m + 1];
  }

  float Mr[16];
#pragma unroll
  for (int k = 0; k < 16; ++k) Mr[k] = 0.f;
#pragma unroll
  for (int j = 0; j < 16; ++j) {
    const float wj = (j & 1) ? wih2[j >> 1].y : wih2[j >> 1].x;
#pragma unroll
    for (int k = 0; k < 16; ++k)
      Mr[k] = __builtin_fmaf(wj, hw2[j * 16 + k], Mr[k]);
  }
  float mbias2 = bias;
#pragma unroll
  for (int j = 0; j < 16; ++j) {
    const float wj = (j & 1) ? wih2[j >> 1].y : wih2[j >> 1].x;
    mbias2 = __builtin_fmaf(wj, hb2[j], mbias2);
  }
  v2f Mr2[8];
#pragma unroll
  for (int m = 0; m < 8; ++m) {
    Mr2[m].x = Mr[2 * m + 0];
    Mr2[m].y = Mr[2 * m + 1];
  }

  v2f xkA[8], xkB[8];
  {
    const float* sA = xstart + (size_t)bu0 * 16;
    const float* sB = xstart + (size_t)bu1 * 16;
#pragma unroll
    for (int m = 0; m < 8; ++m) {
      xkA[m].x = sA[2 * m + 0];
      xkA[m].y = sA[2 * m + 1];
      xkB[m].x = sB[2 * m + 0];
      xkB[m].y = sB[2 * m + 1];
    }
  }

  const size_t obaseA = (size_t)bu0 * (T_LEN * 32) + (lane & 31);
  const size_t obaseB = (size_t)bu1 * (T_LEN * 32) + (lane & 31);

  // ---------------- decoder: 512 steps, both chains ----------------
  CELL_P(wih2, xkA, bias, hA, cA, hkA);
  CELL_P(wih2, xkB, bias, hB, cB, hkB);

  for (int t = 0; t < T_LEN; ++t) {
    v2f PA, QA, PB, QBv;
    PA.x = mbias; PA.y = 0.f; QA.x = 0.f; QA.y = 0.f;
    PB.x = mbias; PB.y = 0.f; QBv.x = 0.f; QBv.y = 0.f;
#pragma unroll
    for (int m = 0; m < 8; m += 2) {
      PA = PKFMA(mr2[m], hkA[m], PA);
      QA = PKFMA(mr2[m + 1], hkA[m + 1], QA);
      PB = PKFMA(mr2[m], hkB[m], PB);
      QBv = PKFMA(mr2[m + 1], hkB[m + 1], QBv);
    }
    float y0A = (PA.x + PA.y) + (QA.x + QA.y);
    float y0B = (PB.x + PB.y) + (QBv.x + QBv.y);
    float yvA = fmaxf(y0A, y0A * sl);
    float yvB = fmaxf(y0B, y0B * sl);

    if (lane < 32) {
      const size_t offA = obaseA + (size_t)(T_LEN - 1 - t) * 32;
      const size_t offB = obaseB + (size_t)(T_LEN - 1 - t) * 32;
      out[offA] = yvA;
      out[offA + OSTRIDE] = yvA;
      out[offB] = yvB;
      out[offB + OSTRIDE] = yvB;
    }

    if (t + 1 < T_LEN) {
      v2f ukA[8], ukB[8];
#pragma unroll
      for (int m = 0; m < 8; ++m) {
        ukA[m].x = rlf(yvA, 32 + 2 * m + 0);
        ukA[m].y = rlf(yvA, 32 + 2 * m + 1);
        ukB[m].x = rlf(yvB, 32 + 2 * m + 0);
        ukB[m].y = rlf(yvB, 32 + 2 * m + 1);
      }
      CELL_P(Mr2, ukA, mbias2, hA, cA, hkA);
      CELL_P(Mr2, ukB, mbias2, hB, cB, hkB);
    }
  }
}

// ===========================================================================
// FALLBACK (x-path) — used only if ws_size is too small for the y2 path.
// ===========================================================================
__device__ __forceinline__ void prenet_row(
    const float* __restrict__ sp,
    const float* __restrict__ w1, const float* __restrict__ b1,
    const float* __restrict__ w2, const float* __restrict__ b2,
    const float* __restrict__ w3, const float* __restrict__ b3,
    float y3[16]) {
  float in[32];
#pragma unroll
  for (int q = 0; q < 8; ++q) {
    float4 v = ((const float4*)sp)[q];
    in[q * 4 + 0] = v.x;
    in[q * 4 + 1] = v.y;
    in[q * 4 + 2] = v.z;
    in[q * 4 + 3] = v.w;
  }
  float y1[16];
#pragma unroll
  for (int j = 0; j < 16; ++j) {
    float a0 = b1[j], a1 = 0.f, a2 = 0.f, a3 = 0.f;
#pragma unroll
    for (int k = 0; k < 32; k += 4) {
      a0 = __builtin_fmaf(w1[j * 32 + k + 0], in[k + 0], a0);
      a1 = __builtin_fmaf(w1[j * 32 + k + 1], in[k + 1], a1);
      a2 = __builtin_fmaf(w1[j * 32 + k + 2], in[k + 2], a2);
      a3 = __builtin_fmaf(w1[j * 32 + k + 3], in[k + 3], a3);
    }
    float s = (a0 + a1) + (a2 + a3);
    y1[j] = s >= 0.f ? s : 0.01f * s;
  }
  float y2[16];
#pragma unroll
  for (int j = 0; j < 16; ++j) {
    float a0 = b2[j], a1 = 0.f, a2 = 0.f, a3 = 0.f;
#pragma unroll
    for (int k = 0; k < 16; k += 4) {
      a0 = __builtin_fmaf(w2[j * 16 + k + 0], y1[k + 0], a0);
      a1 = __builtin_fmaf(w2[j * 16 + k + 1], y1[k + 1], a1);
      a2 = __builtin_fmaf(w2[j * 16 + k + 2], y1[k + 2], a2);
      a3 = __builtin_fmaf(w2[j * 16 + k + 3], y1[k + 3], a3);
    }
    float s = (a0 + a1) + (a2 + a3);
    y2[j] = s >= 0.f ? s : 0.01f * s;
  }
#pragma unroll
  for (int j = 0; j < 16; ++j) {
    float a0 = b3[j], a1 = 0.f, a2 = 0.f, a3 = 0.f;
#pragma unroll
    for (int k = 0; k < 16; k += 4) {
      a0 = __builtin_fmaf(w3[j * 16 + k + 0], y2[k + 0], a0);
      a1 = __builtin_fmaf(w3[j * 16 + k + 1], y2[k + 1], a1);
      a2 = __builtin_fmaf(w3[j * 16 + k + 2], y2[k + 2], a2);
      a3 = __builtin_fmaf(w3[j * 16 + k + 3], y2[k + 3], a3);
    }
    y3[j] = (a0 + a1) + (a2 + a3);
  }
}

__global__ __launch_bounds__(256) void prenet_kernel(
    const float* __restrict__ seq,
    const float* __restrict__ w1, const float* __restrict__ b1,
    const float* __restrict__ w2, const float* __restrict__ b2,
    const float* __restrict__ w3, const float* __restrict__ b3,
    float* __restrict__ xws) {
  const size_t r = (size_t)blockIdx.x * 256 + threadIdx.x;
  float y3[16];
  prenet_row(seq + r * 32, w1, b1, w2, b2, w3, b3, y3);
  float* op = xws + r * 16;
#pragma unroll
  for (int q = 0; q < 4; ++q)
    ((float4*)op)[q] =
        make_float4(y3[q * 4 + 0], y3[q * 4 + 1], y3[q * 4 + 2], y3[q * 4 + 3]);
}

__global__ __launch_bounds__(256, 2) void lstm_rec_kernel(
    const float* __restrict__ Wih, const float* __restrict__ Whh,
    const float* __restrict__ bih, const float* __restrict__ bhh,
    const float* __restrict__ hw1, const float* __restrict__ hb1,
    const float* __restrict__ hw2, const float* __restrict__ hb2,
    const float* __restrict__ pw, const float* __restrict__ pb,
    const float* __restrict__ xws, float* __restrict__ out) {
  const int lane = threadIdx.x & 63;
  const int bu =
      __builtin_amdgcn_readfirstlane(blockIdx.x * 4 + (threadIdx.x >> 6));
  const int hr = lane >> 2;
  const int gi = (lane & 3) * 16 + hr;
  const bool isT = (lane & 3) == 2;

  const float sK = isT ? 2.0f : -1.0f;
  const float sa = isT ? -2.0f : 1.0f;
  const float sb = isT ? 1.0f : 0.0f;

  v2f wih2[8], whh2[8];
#pragma unroll
  for (int m = 0; m < 8; ++m) {
    wih2[m].x = Wih[gi * 16 + 2 * m + 0] * sK;
    wih2[m].y = Wih[gi * 16 + 2 * m + 1] * sK;
    whh2[m].x = Whh[gi * 16 + 2 * m + 0] * sK;
    whh2[m].y = Whh[gi * 16 + 2 * m + 1] * sK;
  }
  const float bias = (bih[gi] + bhh[gi]) * sK;

  float h = 0.f, c = 0.f;
  v2f hk2[8];
#pragma unroll
  for (int m = 0; m < 8; ++m) { hk2[m].x = 0.f; hk2[m].y = 0.f; }

  const float* xb = xws + (size_t)bu * (T_LEN * 16);

  v2f xA2[8], xB2[8];
#pragma unroll
  for (int m = 0; m < 8; ++m) {
    xA2[m].x = xb[2 * m + 0];
    xA2[m].y = xb[2 * m + 1];
  }
  for (int t = 0; t < T_LEN; t += 2) {
    const float* n1 = xb + (size_t)(t + 1) * 16;
#pragma unroll
    for (int m = 0; m < 8; ++m) {
      xB2[m].x = n1[2 * m + 0];
      xB2[m].y = n1[2 * m + 1];
    }
    CELL_P(wih2, xA2, bias, h, c, hk2);
    const int t2 = (t + 2 < T_LEN) ? (t + 2) : (T_LEN - 1);
    const float* n2 = xb + (size_t)t2 * 16;
#pragma unroll
    for (int m = 0; m < 8; ++m) {
      xA2[m].x = n2[2 * m + 0];
      xA2[m].y = n2[2 * m + 1];
    }
    CELL_P(wih2, xB2, bias, h, c, hk2);
  }

  const int mrow = (lane < 32) ? lane : (lane & 15);
  const float* msrc = (lane < 32) ? (pw + mrow * 16) : (hw1 + mrow * 16);
  const float mbias = (lane < 32) ? pb[mrow] : hb1[mrow];
  const float sl = (lane < 32) ? 1.0f : 0.01f;
  v2f mr2[8];
#pragma unroll
  for (int m = 0; m < 8; ++m) {
    mr2[m].x = msrc[2 * m + 0];
    mr2[m].y = msrc[2 * m + 1];
  }

  float Mr[16];
#pragma unroll
  for (int k = 0; k < 16; ++k) Mr[k] = 0.f;
#pragma unroll
  for (int j = 0; j < 16; ++j) {
    const float wj = (j & 1) ? wih2[j >> 1].y : wih2[j >> 1].x;
#pragma unroll
    for (int k = 0; k < 16; ++k)
      Mr[k] = __builtin_fmaf(wj, hw2[j * 16 + k], Mr[k]);
  }
  float mbias2 = bias;
#pragma unroll
  for (int j = 0; j < 16; ++j) {
    const float wj = (j & 1) ? wih2[j >> 1].y : wih2[j >> 1].x;
    mbias2 = __builtin_fmaf(wj, hb2[j], mbias2);
  }
  v2f Mr2[8];
#pragma unroll
  for (int m = 0; m < 8; ++m) {
    Mr2[m].x = Mr[2 * m + 0];
    Mr2[m].y = Mr[2 * m + 1];
  }

  v2f xk2[8];
  {
    const float* src = xb + (size_t)(T_LEN - 1) * 16;
#pragma unroll
    for (int m = 0; m < 8; ++m) {
      xk2[m].x = src[2 * m + 0];
      xk2[m].y = src[2 * m + 1];
    }
  }

  const size_t obase = (size_t)bu * (T_LEN * 32) + (lane & 31);

  CELL_P(wih2, xk2, bias, h, c, hk2);

  for (int t = 0; t < T_LEN; ++t) {
    v2f P, Q;
    P.x = mbias; P.y = 0.f; Q.x = 0.f; Q.y = 0.f;
#pragma unroll
    for (int m = 0; m < 8; m += 2) {
      P = PKFMA(mr2[m], hk2[m], P);
      Q = PKFMA(mr2[m + 1], hk2[m + 1], Q);
    }
    float y0 = (P.x + P.y) + (Q.x + Q.y);
    float yv = fmaxf(y0, y0 * sl);

    if (lane < 32) {
      const size_t off = obase + (size_t)(T_LEN - 1 - t) * 32;
      out[off] = yv;
      out[off + OSTRIDE] = yv;
    }

    if (t + 1 < T_LEN) {
      v2f uk2[8];
#pragma unroll
      for (int m = 0; m < 8; ++m) {
        uk2[m].x = rlf(yv, 32 + 2 * m + 0);
        uk2[m].y = rlf(yv, 32 + 2 * m + 1);
      }
      CELL_P(Mr2, uk2, mbias2, h, c, hk2);
    }
  }
}

extern "C" void kernel_launch(void* const* d_in, const int* in_sizes, int n_in,
                              void* d_out, int out_size, void* d_ws, size_t ws_size,
                              hipStream_t stream) {
  const float* seq = (const float*)d_in[0];
  const float* pre_w1 = (const float*)d_in[1];
  const float* pre_b1 = (const float*)d_in[2];
  const float* pre_w2 = (const float*)d_in[3];
  const float* pre_b2 = (const float*)d_in[4];
  const float* pre_w3 = (const float*)d_in[5];
  const float* pre_b3 = (const float*)d_in[6];
  const float* enc_Wih = (const float*)d_in[7];
  const float* enc_Whh = (const float*)d_in[8];
  const float* enc_bih = (const float*)d_in[9];
  const float* enc_bhh = (const float*)d_in[10];
  const float* h2l_w1 = (const float*)d_in[11];
  const float* h2l_b1 = (const float*)d_in[12];
  const float* h2l_w2 = (const float*)d_in[13];
  const float* h2l_b2 = (const float*)d_in[14];
  const float* post_w = (const float*)d_in[15];
  const float* post_b = (const float*)d_in[16];

  // y2-path workspace: y2 (B*T x 16 fp32 = 64 MiB) + xstart + Wz + Bz
  const size_t y2bytes = (size_t)2048 * 512 * 16 * 4;
  const size_t xsbytes = (size_t)2048 * 16 * 4;
  const size_t wzbytes = 64 * 16 * 4;
  const size_t need = y2bytes + xsbytes + wzbytes + 64 * 4;

  if (ws_size >= need) {
    float* y2g = (float*)d_ws;
    float* xstart = (float*)((char*)d_ws + y2bytes);
    float* Wz = (float*)((char*)d_ws + y2bytes + xsbytes);
    float* Bz = (float*)((char*)d_ws + y2bytes + xsbytes + wzbytes);

    setup_kernel<<<dim3(1), dim3(64), 0, stream>>>(
        enc_Wih, enc_bih, enc_bhh, pre_w3, pre_b3, Wz, Bz);

    prenet_y2_kernel<<<dim3(4096), dim3(256), 0, stream>>>(
        seq, pre_w1, pre_b1, pre_w2, pre_b2, pre_w3, pre_b3, y2g, xstart);

    // 2 batch elements per wave: 1024 waves total = 1 wave/SIMD exactly.
    lstm_rec_z2_kernel<<<dim3(256), dim3(256), 0, stream>>>(
        enc_Whh, enc_Wih, enc_bih, enc_bhh, h2l_w1, h2l_b1, h2l_w2, h2l_b2,
        post_w, post_b, Wz, Bz, y2g, xstart, (float*)d_out);
  } else {
    float* xws = (float*)d_ws;  // (B*T, 16) fp32 = 64 MiB

    prenet_kernel<<<dim3(4096), dim3(256), 0, stream>>>(
        seq, pre_w1, pre_b1, pre_w2, pre_b2, pre_w3, pre_b3, xws);

    lstm_rec_kernel<<<dim3(512), dim3(256), 0, stream>>>(
        enc_Wih, enc_Whh, enc_bih, enc_bhh, h2l_w1, h2l_b1, h2l_w2, h2l_b2,
        post_w, post_b, xws, (float*)d_out);
  }
}

// Round 10
// 711.605 us; speedup vs baseline: 1.2012x; 1.2012x over previous
//
#include <hip/hip_runtime.h>

#define T_LEN 512
#define OSTRIDE ((size_t)2048 * 512 * 32)  // elements per output copy

typedef float v2f __attribute__((ext_vector_type(2)));
#define PKFMA(a, b, c) __builtin_elementwise_fma((a), (b), (c))

__device__ __forceinline__ float rlf(float v, int l) {
  return __int_as_float(__builtin_amdgcn_readlane(__float_as_int(v), l));
}
// quad_perm broadcast of quad-lane sel (0..3): ctrl = sel * 0x55
#define QB(v, pat) __int_as_float(__builtin_amdgcn_mov_dpp(__float_as_int(v), (pat), 0xF, 0xF, false))

// ===========================================================================
// Setup kernel (1 block, 64 threads): compose the z-gate matrix.
//   W_z[g][k] = sK(g) * sum_j Wih[g][j] * W3[j][k]
//   b_z[g]    = sK(g) * (Wih[g]·b3 + bih[g] + bhh[g])
// Valid because pre-net layer 3 has NO activation: z = W_z@y2 + b_z.
// ===========================================================================
__global__ __launch_bounds__(64) void setup_kernel(
    const float* __restrict__ Wih, const float* __restrict__ bih,
    const float* __restrict__ bhh, const float* __restrict__ w3,
    const float* __restrict__ b3, float* __restrict__ Wz,
    float* __restrict__ Bz) {
  const int g = threadIdx.x;  // 0..63
  const float sK = ((g >> 4) == 2) ? 2.0f : -1.0f;
  float acc[16];
#pragma unroll
  for (int k = 0; k < 16; ++k) acc[k] = 0.f;
  float bz = bih[g] + bhh[g];
#pragma unroll
  for (int j = 0; j < 16; ++j) {
    const float wij = Wih[g * 16 + j];
#pragma unroll
    for (int k = 0; k < 16; ++k)
      acc[k] = __builtin_fmaf(wij, w3[j * 16 + k], acc[k]);
    bz = __builtin_fmaf(wij, b3[j], bz);
  }
#pragma unroll
  for (int k = 0; k < 16; ++k) Wz[g * 16 + k] = sK * acc[k];
  Bz[g] = sK * bz;
}

// ===========================================================================
// Pre-net kernel (phase A only): layers 1-2 -> y2 to GLOBAL (64 MB, f32,
// bit-exact), xstart (true y3) for the t==T-1 row.
// ===========================================================================
__global__ __launch_bounds__(256) void prenet_y2_kernel(
    const float* __restrict__ seq,
    const float* __restrict__ w1, const float* __restrict__ b1,
    const float* __restrict__ w2, const float* __restrict__ b2,
    const float* __restrict__ w3, const float* __restrict__ b3,
    float* __restrict__ y2g, float* __restrict__ xstart) {
  const int tid = threadIdx.x;
  const size_t r = (size_t)blockIdx.x * 256 + tid;

  const float* sp = seq + r * 32;
  float in[32];
#pragma unroll
  for (int q = 0; q < 8; ++q) {
    float4 v = ((const float4*)sp)[q];
    in[q * 4 + 0] = v.x;
    in[q * 4 + 1] = v.y;
    in[q * 4 + 2] = v.z;
    in[q * 4 + 3] = v.w;
  }

  float y1[16];
#pragma unroll
  for (int j = 0; j < 16; ++j) {
    float a0 = b1[j], a1 = 0.f, a2 = 0.f, a3 = 0.f;
#pragma unroll
    for (int k = 0; k < 32; k += 4) {
      a0 = __builtin_fmaf(w1[j * 32 + k + 0], in[k + 0], a0);
      a1 = __builtin_fmaf(w1[j * 32 + k + 1], in[k + 1], a1);
      a2 = __builtin_fmaf(w1[j * 32 + k + 2], in[k + 2], a2);
      a3 = __builtin_fmaf(w1[j * 32 + k + 3], in[k + 3], a3);
    }
    float s = (a0 + a1) + (a2 + a3);
    y1[j] = s >= 0.f ? s : 0.01f * s;
  }

  float y2[16];
#pragma unroll
  for (int j = 0; j < 16; ++j) {
    float a0 = b2[j], a1 = 0.f, a2 = 0.f, a3 = 0.f;
#pragma unroll
    for (int k = 0; k < 16; k += 4) {
      a0 = __builtin_fmaf(w2[j * 16 + k + 0], y1[k + 0], a0);
      a1 = __builtin_fmaf(w2[j * 16 + k + 1], y1[k + 1], a1);
      a2 = __builtin_fmaf(w2[j * 16 + k + 2], y1[k + 2], a2);
      a3 = __builtin_fmaf(w2[j * 16 + k + 3], y1[k + 3], a3);
    }
    float s = (a0 + a1) + (a2 + a3);
    y2[j] = s >= 0.f ? s : 0.01f * s;
  }

  float* op = y2g + r * 16;
#pragma unroll
  for (int q = 0; q < 4; ++q)
    ((float4*)op)[q] = make_float4(y2[q * 4 + 0], y2[q * 4 + 1],
                                   y2[q * 4 + 2], y2[q * 4 + 3]);

  // xstart (decoder start vector) needs true y3, only at t == T-1
  if ((r & (T_LEN - 1)) == (T_LEN - 1)) {
    float y3[16];
#pragma unroll
    for (int j = 0; j < 16; ++j) {
      float a0 = b3[j], a1 = 0.f, a2 = 0.f, a3 = 0.f;
#pragma unroll
      for (int k = 0; k < 16; k += 4) {
        a0 = __builtin_fmaf(w3[j * 16 + k + 0], y2[k + 0], a0);
        a1 = __builtin_fmaf(w3[j * 16 + k + 1], y2[k + 1], a1);
        a2 = __builtin_fmaf(w3[j * 16 + k + 2], y2[k + 2], a2);
        a3 = __builtin_fmaf(w3[j * 16 + k + 3], y2[k + 3], a3);
      }
      y3[j] = (a0 + a1) + (a2 + a3);
    }
    float* xs = xstart + (r >> 9) * 16;
#pragma unroll
    for (int q = 0; q < 4; ++q)
      ((float4*)xs)[q] = make_float4(y3[q * 4 + 0], y3[q * 4 + 1],
                                     y3[q * 4 + 2], y3[q * 4 + 3]);
  }
}

// ===========================================================================
// Recurrence kernel — fused z-gate GEMV, pinned prefetch (r5), plus:
// zv SOFTWARE-PIPELINED BY ONE STEP. ZGEMV(t+1) (which depends only on y2,
// not on h) is computed BEFORE CELLZ(t) inside the same barrier region; the
// scheduler fills the act-chain dependency stalls with znext's independent
// pkfmas. Identical operands and accumulation order -> bit-exact.
// This is the measured-best configuration (714.2 us total, rec 377 us).
// ===========================================================================
#define ACTBODY()                                                           \
  do {                                                                      \
    float ee = __expf(g);                                                   \
    float rr = __builtin_amdgcn_rcpf(1.0f + ee);                            \
    float act = __builtin_fmaf(sa, rr, sb);                                 \
    float ii = QB(act, 0x00);                                               \
    float ff = QB(act, 0x55);                                               \
    float gg = QB(act, 0xAA);                                               \
    float oo = QB(act, 0xFF);                                               \
    c = __builtin_fmaf(ff, c, ii * gg);                                     \
    float th = __builtin_fmaf(                                              \
        -2.0f, __builtin_amdgcn_rcpf(1.0f + __expf(c + c)), 1.0f);          \
    h = oo * th;                                                            \
    _Pragma("unroll") for (int m = 0; m < 8; ++m) {                         \
      hk2[m].x = rlf(h, 8 * m);                                             \
      hk2[m].y = rlf(h, 8 * m + 4);                                         \
    }                                                                       \
  } while (0)

#define CELLZ(ZV)                                                           \
  do {                                                                      \
    v2f A, Bv;                                                              \
    A.x = (ZV); A.y = 0.f; Bv.x = 0.f; Bv.y = 0.f;                          \
    _Pragma("unroll") for (int m = 0; m < 8; m += 2) {                      \
      A = PKFMA(whh2[m], hk2[m], A);                                        \
      Bv = PKFMA(whh2[m + 1], hk2[m + 1], Bv);                              \
    }                                                                       \
    float g = (A.x + A.y) + (Bv.x + Bv.y);                                  \
    ACTBODY();                                                              \
  } while (0)

#define CELL(WX2, XA2, BB)                                                  \
  do {                                                                      \
    v2f A, Bv;                                                              \
    A.x = (BB); A.y = 0.f; Bv.x = 0.f; Bv.y = 0.f;                          \
    _Pragma("unroll") for (int m = 0; m < 8; m += 2) {                      \
      A = PKFMA(WX2[m], XA2[m], A);                                         \
      Bv = PKFMA(WX2[m + 1], XA2[m + 1], Bv);                               \
    }                                                                       \
    _Pragma("unroll") for (int m = 0; m < 8; m += 2) {                      \
      A = PKFMA(whh2[m], hk2[m], A);                                        \
      Bv = PKFMA(whh2[m + 1], hk2[m + 1], Bv);                              \
    }                                                                       \
    float g = (A.x + A.y) + (Bv.x + Bv.y);                                  \
    ACTBODY();                                                              \
  } while (0)

// z-gate GEMV from a prefetched y2 row (4 float4). Bit-exact replica of the
// old prenet phase-B order: A.x seeded with bz; A takes k={4q,4q+1},
// Bv takes k={4q+2,4q+3}; reduce (A.x+A.y)+(Bv.x+Bv.y).
#define ZGEMV(YQ, OUTV)                                                     \
  do {                                                                      \
    v2f A, Bv;                                                              \
    A.x = bz; A.y = 0.f; Bv.x = 0.f; Bv.y = 0.f;                            \
    _Pragma("unroll") for (int q = 0; q < 4; ++q) {                         \
      float4 v = (YQ)[q];                                                   \
      v2f ylo, yhi;                                                         \
      ylo.x = v.x; ylo.y = v.y; yhi.x = v.z; yhi.y = v.w;                   \
      A = PKFMA(wz2[2 * q + 0], ylo, A);                                    \
      Bv = PKFMA(wz2[2 * q + 1], yhi, Bv);                                  \
    }                                                                       \
    OUTV = (A.x + A.y) + (Bv.x + Bv.y);                                     \
  } while (0)

__global__ __launch_bounds__(256, 2) void lstm_rec_z_kernel(
    const float* __restrict__ Whh, const float* __restrict__ Wih,
    const float* __restrict__ bih, const float* __restrict__ bhh,
    const float* __restrict__ hw1, const float* __restrict__ hb1,
    const float* __restrict__ hw2, const float* __restrict__ hb2,
    const float* __restrict__ pw, const float* __restrict__ pb,
    const float* __restrict__ Wz, const float* __restrict__ Bz,
    const float* __restrict__ y2g, const float* __restrict__ xstart,
    float* __restrict__ out) {
  const int lane = threadIdx.x & 63;
  const int bu =
      __builtin_amdgcn_readfirstlane(blockIdx.x * 4 + (threadIdx.x >> 6));
  const int hr = lane >> 2;             // h index 0..15 (quad id)
  const int gi = (lane & 3) * 16 + hr;  // gate row 0..63
  const bool isT = (lane & 3) == 2;     // quad-lane 2 = g gate (tanh)

  const float sK = isT ? 2.0f : -1.0f;
  const float sa = isT ? -2.0f : 1.0f;
  const float sb = isT ? 1.0f : 0.0f;

  v2f whh2[8];
#pragma unroll
  for (int m = 0; m < 8; ++m) {
    whh2[m].x = Whh[gi * 16 + 2 * m + 0] * sK;
    whh2[m].y = Whh[gi * 16 + 2 * m + 1] * sK;
  }

  // z-gate row (Wz/Bz already include sK from setup_kernel)
  v2f wz2[8];
  {
    const float4* wzv = (const float4*)(Wz + gi * 16);
#pragma unroll
    for (int q = 0; q < 4; ++q) {
      float4 v = wzv[q];
      wz2[2 * q + 0].x = v.x;
      wz2[2 * q + 0].y = v.y;
      wz2[2 * q + 1].x = v.z;
      wz2[2 * q + 1].y = v.w;
    }
  }
  const float bz = Bz[gi];

  float h = 0.f, c = 0.f;
  v2f hk2[8];
#pragma unroll
  for (int m = 0; m < 8; ++m) { hk2[m].x = 0.f; hk2[m].y = 0.f; }

  // -------- encoder: 512 steps, rows prefetched 4 ahead, zv pipelined 1 ----
  const float4* yb = (const float4*)(y2g + (size_t)bu * (T_LEN * 16));
  float4 yq[4][4];
#pragma unroll
  for (int u = 0; u < 4; ++u) {
#pragma unroll
    for (int q = 0; q < 4; ++q) yq[u][q] = yb[u * 4 + q];
  }
  __builtin_amdgcn_sched_barrier(0);  // prologue loads issue before the loop

  float zcur;
  ZGEMV(yq[0], zcur);  // row 0

  for (int t0 = 0; t0 < T_LEN; t0 += 4) {
#pragma unroll
    for (int u = 0; u < 4; ++u) {
      // znext (row t0+u+1) is h-independent: same barrier region as CELLZ
      // so its pkfmas fill the act-chain stall slots. At the final step the
      // ring slot holds a clamped duplicate of row 511; znext is discarded.
      float znext;
      ZGEMV(yq[(u + 1) & 3], znext);
      CELLZ(zcur);  // row t0+u
      int tn = t0 + u + 4;
      tn = tn < T_LEN ? tn : (T_LEN - 1);  // tail reload of row 511, harmless
#pragma unroll
      for (int q = 0; q < 4; ++q) yq[u][q] = yb[(size_t)tn * 4 + q];
      // Pin issue order: refill loads may NOT sink past here (keeps the ring
      // 4 rows ahead; waitcnt stays compiler-counted).
      __builtin_amdgcn_sched_barrier(0);
      zcur = znext;
    }
  }

  // ---------------- decoder setup ----------------
  v2f wih2[8];
#pragma unroll
  for (int m = 0; m < 8; ++m) {
    wih2[m].x = Wih[gi * 16 + 2 * m + 0] * sK;
    wih2[m].y = Wih[gi * 16 + 2 * m + 1] * sK;
  }
  const float bias = (bih[gi] + bhh[gi]) * sK;

  const int mrow = (lane < 32) ? lane : (lane & 15);
  const float* msrc = (lane < 32) ? (pw + mrow * 16) : (hw1 + mrow * 16);
  const float mbias = (lane < 32) ? pb[mrow] : hb1[mrow];
  const float sl = (lane < 32) ? 1.0f : 0.01f;
  v2f mr2[8];
#pragma unroll
  for (int m = 0; m < 8; ++m) {
    mr2[m].x = msrc[2 * m + 0];
    mr2[m].y = msrc[2 * m + 1];
  }

  float Mr[16];
#pragma unroll
  for (int k = 0; k < 16; ++k) Mr[k] = 0.f;
#pragma unroll
  for (int j = 0; j < 16; ++j) {
    const float wj = (j & 1) ? wih2[j >> 1].y : wih2[j >> 1].x;
#pragma unroll
    for (int k = 0; k < 16; ++k)
      Mr[k] = __builtin_fmaf(wj, hw2[j * 16 + k], Mr[k]);
  }
  float mbias2 = bias;
#pragma unroll
  for (int j = 0; j < 16; ++j) {
    const float wj = (j & 1) ? wih2[j >> 1].y : wih2[j >> 1].x;
    mbias2 = __builtin_fmaf(wj, hb2[j], mbias2);
  }
  v2f Mr2[8];
#pragma unroll
  for (int m = 0; m < 8; ++m) {
    Mr2[m].x = Mr[2 * m + 0];
    Mr2[m].y = Mr[2 * m + 1];
  }

  v2f xk2[8];
  {
    const float* src = xstart + (size_t)bu * 16;
#pragma unroll
    for (int m = 0; m < 8; ++m) {
      xk2[m].x = src[2 * m + 0];
      xk2[m].y = src[2 * m + 1];
    }
  }

  const size_t obase = (size_t)bu * (T_LEN * 32) + (lane & 31);

  // ---------------- decoder: 512 steps ----------------
  CELL(wih2, xk2, bias);

  for (int t = 0; t < T_LEN; ++t) {
    v2f P, Q;
    P.x = mbias; P.y = 0.f; Q.x = 0.f; Q.y = 0.f;
#pragma unroll
    for (int m = 0; m < 8; m += 2) {
      P = PKFMA(mr2[m], hk2[m], P);
      Q = PKFMA(mr2[m + 1], hk2[m + 1], Q);
    }
    float y0 = (P.x + P.y) + (Q.x + Q.y);
    float yv = fmaxf(y0, y0 * sl);

    if (lane < 32) {
      const size_t off = obase + (size_t)(T_LEN - 1 - t) * 32;
      out[off] = yv;
      out[off + OSTRIDE] = yv;
    }

    if (t + 1 < T_LEN) {
      v2f uk2[8];
#pragma unroll
      for (int m = 0; m < 8; ++m) {
        uk2[m].x = rlf(yv, 32 + 2 * m + 0);
        uk2[m].y = rlf(yv, 32 + 2 * m + 1);
      }
      CELL(Mr2, uk2, mbias2);
    }
  }
}

// ===========================================================================
// FALLBACK (x-path) — used only if ws_size is too small for the y2 path.
// ===========================================================================
__device__ __forceinline__ void prenet_row(
    const float* __restrict__ sp,
    const float* __restrict__ w1, const float* __restrict__ b1,
    const float* __restrict__ w2, const float* __restrict__ b2,
    const float* __restrict__ w3, const float* __restrict__ b3,
    float y3[16]) {
  float in[32];
#pragma unroll
  for (int q = 0; q < 8; ++q) {
    float4 v = ((const float4*)sp)[q];
    in[q * 4 + 0] = v.x;
    in[q * 4 + 1] = v.y;
    in[q * 4 + 2] = v.z;
    in[q * 4 + 3] = v.w;
  }
  float y1[16];
#pragma unroll
  for (int j = 0; j < 16; ++j) {
    float a0 = b1[j], a1 = 0.f, a2 = 0.f, a3 = 0.f;
#pragma unroll
    for (int k = 0; k < 32; k += 4) {
      a0 = __builtin_fmaf(w1[j * 32 + k + 0], in[k + 0], a0);
      a1 = __builtin_fmaf(w1[j * 32 + k + 1], in[k + 1], a1);
      a2 = __builtin_fmaf(w1[j * 32 + k + 2], in[k + 2], a2);
      a3 = __builtin_fmaf(w1[j * 32 + k + 3], in[k + 3], a3);
    }
    float s = (a0 + a1) + (a2 + a3);
    y1[j] = s >= 0.f ? s : 0.01f * s;
  }
  float y2[16];
#pragma unroll
  for (int j = 0; j < 16; ++j) {
    float a0 = b2[j], a1 = 0.f, a2 = 0.f, a3 = 0.f;
#pragma unroll
    for (int k = 0; k < 16; k += 4) {
      a0 = __builtin_fmaf(w2[j * 16 + k + 0], y1[k + 0], a0);
      a1 = __builtin_fmaf(w2[j * 16 + k + 1], y1[k + 1], a1);
      a2 = __builtin_fmaf(w2[j * 16 + k + 2], y1[k + 2], a2);
      a3 = __builtin_fmaf(w2[j * 16 + k + 3], y1[k + 3], a3);
    }
    float s = (a0 + a1) + (a2 + a3);
    y2[j] = s >= 0.f ? s : 0.01f * s;
  }
#pragma unroll
  for (int j = 0; j < 16; ++j) {
    float a0 = b3[j], a1 = 0.f, a2 = 0.f, a3 = 0.f;
#pragma unroll
    for (int k = 0; k < 16; k += 4) {
      a0 = __builtin_fmaf(w3[j * 16 + k + 0], y2[k + 0], a0);
      a1 = __builtin_fmaf(w3[j * 16 + k + 1], y2[k + 1], a1);
      a2 = __builtin_fmaf(w3[j * 16 + k + 2], y2[k + 2], a2);
      a3 = __builtin_fmaf(w3[j * 16 + k + 3], y2[k + 3], a3);
    }
    y3[j] = (a0 + a1) + (a2 + a3);
  }
}

__global__ __launch_bounds__(256) void prenet_kernel(
    const float* __restrict__ seq,
    const float* __restrict__ w1, const float* __restrict__ b1,
    const float* __restrict__ w2, const float* __restrict__ b2,
    const float* __restrict__ w3, const float* __restrict__ b3,
    float* __restrict__ xws) {
  const size_t r = (size_t)blockIdx.x * 256 + threadIdx.x;
  float y3[16];
  prenet_row(seq + r * 32, w1, b1, w2, b2, w3, b3, y3);
  float* op = xws + r * 16;
#pragma unroll
  for (int q = 0; q < 4; ++q)
    ((float4*)op)[q] =
        make_float4(y3[q * 4 + 0], y3[q * 4 + 1], y3[q * 4 + 2], y3[q * 4 + 3]);
}

__global__ __launch_bounds__(256, 2) void lstm_rec_kernel(
    const float* __restrict__ Wih, const float* __restrict__ Whh,
    const float* __restrict__ bih, const float* __restrict__ bhh,
    const float* __restrict__ hw1, const float* __restrict__ hb1,
    const float* __restrict__ hw2, const float* __restrict__ hb2,
    const float* __restrict__ pw, const float* __restrict__ pb,
    const float* __restrict__ xws, float* __restrict__ out) {
  const int lane = threadIdx.x & 63;
  const int bu =
      __builtin_amdgcn_readfirstlane(blockIdx.x * 4 + (threadIdx.x >> 6));
  const int hr = lane >> 2;
  const int gi = (lane & 3) * 16 + hr;
  const bool isT = (lane & 3) == 2;

  const float sK = isT ? 2.0f : -1.0f;
  const float sa = isT ? -2.0f : 1.0f;
  const float sb = isT ? 1.0f : 0.0f;

  v2f wih2[8], whh2[8];
#pragma unroll
  for (int m = 0; m < 8; ++m) {
    wih2[m].x = Wih[gi * 16 + 2 * m + 0] * sK;
    wih2[m].y = Wih[gi * 16 + 2 * m + 1] * sK;
    whh2[m].x = Whh[gi * 16 + 2 * m + 0] * sK;
    whh2[m].y = Whh[gi * 16 + 2 * m + 1] * sK;
  }
  const float bias = (bih[gi] + bhh[gi]) * sK;

  float h = 0.f, c = 0.f;
  v2f hk2[8];
#pragma unroll
  for (int m = 0; m < 8; ++m) { hk2[m].x = 0.f; hk2[m].y = 0.f; }

  const float* xb = xws + (size_t)bu * (T_LEN * 16);

  v2f xA2[8], xB2[8];
#pragma unroll
  for (int m = 0; m < 8; ++m) {
    xA2[m].x = xb[2 * m + 0];
    xA2[m].y = xb[2 * m + 1];
  }
  for (int t = 0; t < T_LEN; t += 2) {
    const float* n1 = xb + (size_t)(t + 1) * 16;
#pragma unroll
    for (int m = 0; m < 8; ++m) {
      xB2[m].x = n1[2 * m + 0];
      xB2[m].y = n1[2 * m + 1];
    }
    CELL(wih2, xA2, bias);
    const int t2 = (t + 2 < T_LEN) ? (t + 2) : (T_LEN - 1);
    const float* n2 = xb + (size_t)t2 * 16;
#pragma unroll
    for (int m = 0; m < 8; ++m) {
      xA2[m].x = n2[2 * m + 0];
      xA2[m].y = n2[2 * m + 1];
    }
    CELL(wih2, xB2, bias);
  }

  const int mrow = (lane < 32) ? lane : (lane & 15);
  const float* msrc = (lane < 32) ? (pw + mrow * 16) : (hw1 + mrow * 16);
  const float mbias = (lane < 32) ? pb[mrow] : hb1[mrow];
  const float sl = (lane < 32) ? 1.0f : 0.01f;
  v2f mr2[8];
#pragma unroll
  for (int m = 0; m < 8; ++m) {
    mr2[m].x = msrc[2 * m + 0];
    mr2[m].y = msrc[2 * m + 1];
  }

  float Mr[16];
#pragma unroll
  for (int k = 0; k < 16; ++k) Mr[k] = 0.f;
#pragma unroll
  for (int j = 0; j < 16; ++j) {
    const float wj = (j & 1) ? wih2[j >> 1].y : wih2[j >> 1].x;
#pragma unroll
    for (int k = 0; k < 16; ++k)
      Mr[k] = __builtin_fmaf(wj, hw2[j * 16 + k], Mr[k]);
  }
  float mbias2 = bias;
#pragma unroll
  for (int j = 0; j < 16; ++j) {
    const float wj = (j & 1) ? wih2[j >> 1].y : wih2[j >> 1].x;
    mbias2 = __builtin_fmaf(wj, hb2[j], mbias2);
  }
  v2f Mr2[8];
#pragma unroll
  for (int m = 0; m < 8; ++m) {
    Mr2[m].x = Mr[2 * m + 0];
    Mr2[m].y = Mr[2 * m + 1];
  }

  v2f xk2[8];
  {
    const float* src = xb + (size_t)(T_LEN - 1) * 16;
#pragma unroll
    for (int m = 0; m < 8; ++m) {
      xk2[m].x = src[2 * m + 0];
      xk2[m].y = src[2 * m + 1];
    }
  }

  const size_t obase = (size_t)bu * (T_LEN * 32) + (lane & 31);

  CELL(wih2, xk2, bias);

  for (int t = 0; t < T_LEN; ++t) {
    v2f P, Q;
    P.x = mbias; P.y = 0.f; Q.x = 0.f; Q.y = 0.f;
#pragma unroll
    for (int m = 0; m < 8; m += 2) {
      P = PKFMA(mr2[m], hk2[m], P);
      Q = PKFMA(mr2[m + 1], hk2[m + 1], Q);
    }
    float y0 = (P.x + P.y) + (Q.x + Q.y);
    float yv = fmaxf(y0, y0 * sl);

    if (lane < 32) {
      const size_t off = obase + (size_t)(T_LEN - 1 - t) * 32;
      out[off] = yv;
      out[off + OSTRIDE] = yv;
    }

    if (t + 1 < T_LEN) {
      v2f uk2[8];
#pragma unroll
      for (int m = 0; m < 8; ++m) {
        uk2[m].x = rlf(yv, 32 + 2 * m + 0);
        uk2[m].y = rlf(yv, 32 + 2 * m + 1);
      }
      CELL(Mr2, uk2, mbias2);
    }
  }
}

extern "C" void kernel_launch(void* const* d_in, const int* in_sizes, int n_in,
                              void* d_out, int out_size, void* d_ws, size_t ws_size,
                              hipStream_t stream) {
  const float* seq = (const float*)d_in[0];
  const float* pre_w1 = (const float*)d_in[1];
  const float* pre_b1 = (const float*)d_in[2];
  const float* pre_w2 = (const float*)d_in[3];
  const float* pre_b2 = (const float*)d_in[4];
  const float* pre_w3 = (const float*)d_in[5];
  const float* pre_b3 = (const float*)d_in[6];
  const float* enc_Wih = (const float*)d_in[7];
  const float* enc_Whh = (const float*)d_in[8];
  const float* enc_bih = (const float*)d_in[9];
  const float* enc_bhh = (const float*)d_in[10];
  const float* h2l_w1 = (const float*)d_in[11];
  const float* h2l_b1 = (const float*)d_in[12];
  const float* h2l_w2 = (const float*)d_in[13];
  const float* h2l_b2 = (const float*)d_in[14];
  const float* post_w = (const float*)d_in[15];
  const float* post_b = (const float*)d_in[16];

  // y2-path workspace: y2 (B*T x 16 fp32 = 64 MiB) + xstart + Wz + Bz
  const size_t y2bytes = (size_t)2048 * 512 * 16 * 4;
  const size_t xsbytes = (size_t)2048 * 16 * 4;
  const size_t wzbytes = 64 * 16 * 4;
  const size_t need = y2bytes + xsbytes + wzbytes + 64 * 4;

  if (ws_size >= need) {
    float* y2g = (float*)d_ws;
    float* xstart = (float*)((char*)d_ws + y2bytes);
    float* Wz = (float*)((char*)d_ws + y2bytes + xsbytes);
    float* Bz = (float*)((char*)d_ws + y2bytes + xsbytes + wzbytes);

    setup_kernel<<<dim3(1), dim3(64), 0, stream>>>(
        enc_Wih, enc_bih, enc_bhh, pre_w3, pre_b3, Wz, Bz);

    prenet_y2_kernel<<<dim3(4096), dim3(256), 0, stream>>>(
        seq, pre_w1, pre_b1, pre_w2, pre_b2, pre_w3, pre_b3, y2g, xstart);

    lstm_rec_z_kernel<<<dim3(512), dim3(256), 0, stream>>>(
        enc_Whh, enc_Wih, enc_bih, enc_bhh, h2l_w1, h2l_b1, h2l_w2, h2l_b2,
        post_w, post_b, Wz, Bz, y2g, xstart, (float*)d_out);
  } else {
    float* xws = (float*)d_ws;  // (B*T, 16) fp32 = 64 MiB

    prenet_kernel<<<dim3(4096), dim3(256), 0, stream>>>(
        seq, pre_w1, pre_b1, pre_w2, pre_b2, pre_w3, pre_b3, xws);

    lstm_rec_kernel<<<dim3(512), dim3(256), 0, stream>>>(
        enc_Wih, enc_Whh, enc_bih, enc_bhh, h2l_w1, h2l_b1, h2l_w2, h2l_b2,
        post_w, post_b, xws, (float*)d_out);
  }
}